// Round 6
// baseline (40550.375 us; speedup 1.0000x reference)
//
#include <hip/hip_runtime.h>
#include <math.h>

// ---------------------------------------------------------------------------
// DefaultHumanoidGRUCritic on MI355X — round 6
//
// Round-5 measured: VGPR_Count=68 < 96 floats of per-lane weights => the
// compiler sank weight loads into the K-loop (re-read from L1/L2 every step,
// ~196KB/WG/step on the critical path). Round-6:
//   * PIN weights in VGPRs via asm volatile("" : "+v"(x)) after the pre-loop
//     load; __launch_bounds__(512,1) for a 512-VGPR budget (grid = 48 WGs).
//   * ig0 prefetched ONE STEP AHEAD into double-buffered igbuf (HBM latency
//     off the critical path).
//   * ONE __syncthreads per step: hbuf/igbuf double-buffered by step parity.
//   * B issues both ring first-probes before either verify loop (parallel
//     LLC rounds).
// Everything else is the round-5 proven structure: fence-free tagged 8B
// relaxed agent atomics, conflict-free LDS mapping (float4 chunks jj+16*i),
// A=16 WGs x 512 (32 el/WG), B=32 WGs x 512 (16 el/WG, ih/hh half-split),
// ring0=2048 slots + coarse cntB throttle, ring1=8 slots.
// ---------------------------------------------------------------------------

#define T_STEPS 16384
#define IN_DIM 341
#define HID 512
#define G3 1536
#define TTILE 16
#define R0 2048
#define R0M (R0-1)
#define R1 8
#define R1M (R1-1)

__device__ __forceinline__ float dot4(float4 a, float4 b) {
  return fmaf(a.x, b.x, fmaf(a.y, b.y, fmaf(a.z, b.z, a.w * b.w)));
}
__device__ __forceinline__ float fast_sigmoid(float x) {
  return __builtin_amdgcn_rcpf(1.0f + __expf(-x));
}
__device__ __forceinline__ float fast_tanh(float x) {
  return fmaf(-2.0f, __builtin_amdgcn_rcpf(1.0f + __expf(2.0f * x)), 1.0f);
}
__device__ __forceinline__ unsigned long long ld_rlx64(const unsigned long long* p) {
  return __hip_atomic_load(p, __ATOMIC_RELAXED, __HIP_MEMORY_SCOPE_AGENT);
}
__device__ __forceinline__ void st_rlx64(unsigned long long* p, unsigned long long v) {
  __hip_atomic_store(p, v, __ATOMIC_RELAXED, __HIP_MEMORY_SCOPE_AGENT);
}
__device__ __forceinline__ unsigned ld_rlx32(const unsigned* p) {
  return __hip_atomic_load(p, __ATOMIC_RELAXED, __HIP_MEMORY_SCOPE_AGENT);
}
__device__ __forceinline__ void st_rlx32(unsigned* p, unsigned v) {
  __hip_atomic_store(p, v, __ATOMIC_RELAXED, __HIP_MEMORY_SCOPE_AGENT);
}
__device__ __forceinline__ unsigned long long pack_tv(unsigned tag, float v) {
  return ((unsigned long long)tag << 32) | (unsigned long long)__float_as_uint(v);
}
// pin a float4's components into VGPRs: value becomes asm-defined, so the
// compiler cannot rematerialize (re-load) it inside the loop.
__device__ __forceinline__ void pin4(float4& v) {
  asm volatile("" : "+v"(v.x), "+v"(v.y), "+v"(v.z), "+v"(v.w));
}
// tagged verify load with backoff: fast path = single load when data present
__device__ __forceinline__ float verify_ld(const unsigned long long* p, unsigned want) {
  unsigned long long w = ld_rlx64(p);
  while ((unsigned)(w >> 32) != want) {
    __builtin_amdgcn_s_sleep(1);
    w = ld_rlx64(p);
  }
  return __uint_as_float((unsigned)w);
}

// ---- k0: concat observations ----------------------------------------------
__global__ __launch_bounds__(384) void concat_kernel(
    const float* __restrict__ p0, const float* __restrict__ p1,
    const float* __restrict__ p2, const float* __restrict__ p3,
    const float* __restrict__ p4, const float* __restrict__ p5,
    const float* __restrict__ p6, const float* __restrict__ p7,
    const float* __restrict__ p8, const float* __restrict__ p9,
    const float* __restrict__ p10, const float* __restrict__ p11,
    const float* __restrict__ p12, float* __restrict__ obs) {
  int t = blockIdx.x;
  int k = threadIdx.x;
  if (k >= IN_DIM) return;
  float v;
  if (k < 21)       v = p0[t*21 + k];
  else if (k < 42)  v = p1[t*21 + (k-21)];
  else if (k < 202) v = p2[t*160 + (k-42)];
  else if (k < 298) v = p3[t*96 + (k-202)];
  else if (k < 301) v = p4[t*3 + (k-298)];
  else if (k < 304) v = p5[t*3 + (k-301)];
  else if (k < 325) v = p6[t*21 + (k-304)];
  else if (k < 328) v = p7[t*3 + (k-325)];
  else if (k < 332) v = p8[t*4 + (k-328)];
  else if (k < 335) v = p9[t*3 + (k-332)];
  else if (k < 338) v = p10[t*3 + (k-335)];
  else if (k < 340) v = p11[t*2 + (k-338)];
  else              v = p12[t];
  obs[(size_t)t*IN_DIM + k] = v;
}

// ---- k1: transpose w_ih0 ---------------------------------------------------
__global__ __launch_bounds__(256) void transpose_kernel(const float* __restrict__ w,
                                                        float* __restrict__ wT) {
  __shared__ float tile[32][33];
  int tx = threadIdx.x;  // 32
  int ty = threadIdx.y;  // 8
  int k = blockIdx.x*32 + tx;
#pragma unroll
  for (int jj = 0; jj < 4; jj++) {
    int r = blockIdx.y*32 + ty*4 + jj;
    tile[ty*4+jj][tx] = (k < IN_DIM) ? w[(size_t)r*IN_DIM + k] : 0.f;
  }
  __syncthreads();
#pragma unroll
  for (int jj = 0; jj < 4; jj++) {
    int kk = blockIdx.x*32 + ty*4 + jj;
    if (kk < IN_DIM) wT[(size_t)kk*G3 + blockIdx.y*32 + tx] = tile[tx][ty*4+jj];
  }
}

// ---- k2: IG0 = obs @ w_ih0^T + b_ih0 --------------------------------------
__global__ __launch_bounds__(256) void ig0_kernel(const float* __restrict__ wT,
                                                  const float* __restrict__ obs,
                                                  const float* __restrict__ b_ih0,
                                                  float* __restrict__ ig0) {
  int o = blockIdx.x*256 + threadIdx.x;
  int t0 = blockIdx.y * TTILE;
  float acc[TTILE];
  float b = b_ih0[o];
#pragma unroll
  for (int tt = 0; tt < TTILE; tt++) acc[tt] = b;
  for (int k = 0; k < IN_DIM; k++) {
    float wv = wT[(size_t)k*G3 + o];
#pragma unroll
    for (int tt = 0; tt < TTILE; tt++)
      acc[tt] = fmaf(obs[(size_t)(t0+tt)*IN_DIM + k], wv, acc[tt]);
  }
#pragma unroll
  for (int tt = 0; tt < TTILE; tt++)
    ig0[(size_t)(t0+tt)*G3 + o] = acc[tt];
}

// ---- k_init: seed ring slot 0 with tagged initial hidden -------------------
__global__ __launch_bounds__(512) void init_kernel(const float* __restrict__ hid,
                                                   unsigned long long* ring0,
                                                   unsigned long long* ring1) {
  int e = threadIdx.x;
  st_rlx64(&ring0[e], pack_tv(0u, hid[e]));
  st_rlx64(&ring1[e], pack_tv(0u, hid[HID + e]));
}

// ---- k3: sequential GRU scan ----------------------------------------------
__global__ __launch_bounds__(512, 1) void seq_kernel(
    const float* __restrict__ ig0, const float* __restrict__ w_hh0,
    const float* __restrict__ b_n0, const float* __restrict__ w_ih1,
    const float* __restrict__ w_hh1, const float* __restrict__ b_ih1,
    const float* __restrict__ b_n1,
    unsigned long long* ring0, unsigned long long* ring1, unsigned* cntB,
    float* __restrict__ h1a, float* __restrict__ d_out) {
  __shared__ float hbuf0[2][HID];
  __shared__ float hbuf1[2][HID];
  __shared__ float igbuf[2][96];
  const int tid = threadIdx.x;

  if ((int)blockIdx.x < 16) {
    // ================= stage A: layer-0 GRU =================
    const int wg = blockIdx.x;
    const int g  = tid >> 4;        // 0..31: element group
    const int jj = tid & 15;        // lane within group
    const int eg = wg*32 + g;       // global h0 element
    const bool leader = (jj == 0);
    const int iggate = tid >> 5, ige = tid & 31;  // for tid<96 ig prefetch
    // weights as float4 chunks jj+16*i (k-values 4jj+64i+c), pinned in VGPRs
    float4 wr[8], wz[8], wn[8];
    {
      const float4* pr_ = (const float4*)(w_hh0 + (size_t)eg*HID);
      const float4* pz_ = (const float4*)(w_hh0 + (size_t)(512+eg)*HID);
      const float4* pn_ = (const float4*)(w_hh0 + (size_t)(1024+eg)*HID);
#pragma unroll
      for (int i = 0; i < 8; i++) {
        wr[i] = pr_[jj + 16*i]; wz[i] = pz_[jj + 16*i]; wn[i] = pn_[jj + 16*i];
        pin4(wr[i]); pin4(wz[i]); pin4(wn[i]);
      }
    }
    const float bn = b_n0[eg];
    // preload igbuf for step 0
    if (tid < 96) igbuf[0][tid] = ig0[(size_t)iggate*HID + wg*32 + ige];
    for (int t = 0; t < T_STEPS; t++) {
      const int p = t & 1;
      // prefetch ig for step t+1 (registers now, LDS after the barrier)
      float igpre = 0.f;
      if (tid < 96) {
        int tn = (t+1 < T_STEPS) ? t+1 : t;
        igpre = ig0[(size_t)tn*G3 + iggate*HID + wg*32 + ige];
      }
      // ring-overwrite throttle: steps [t,t+511] overwrite tags <= t+512-R0;
      // every B WG must have consumed them (cntB >= tag).
      if ((t & 511) == 0 && t >= R0 && tid < 64) {
        const unsigned need = (unsigned)(t + 512 - R0);
        while (true) {
          unsigned v = ld_rlx32(&cntB[tid & 31]);
          if (__ballot(v >= need) == ~0ull) break;
          __builtin_amdgcn_s_sleep(16);
        }
      }
      // stage h0^(t): thread i verifies element i
      hbuf0[p][tid] = verify_ld(&ring0[(size_t)(t & R0M)*HID + tid], (unsigned)t);
      __syncthreads();   // the ONLY barrier per step
      float pr=0.f, pz=0.f, pn=0.f;
      const float4* hp = (const float4*)hbuf0[p];
#pragma unroll
      for (int i = 0; i < 8; i++) {
        float4 hv = hp[jj + 16*i];   // words 4jj+64i: conflict-free
        pr += dot4(wr[i],hv); pz += dot4(wz[i],hv); pn += dot4(wn[i],hv);
      }
#pragma unroll
      for (int s = 1; s < 16; s <<= 1) {
        pr += __shfl_xor(pr, s, 16);
        pz += __shfl_xor(pz, s, 16);
        pn += __shfl_xor(pn, s, 16);
      }
      if (leader) {
        float r = fast_sigmoid(igbuf[p][g] + pr);
        float z = fast_sigmoid(igbuf[p][32+g] + pz);
        float n = fast_tanh(igbuf[p][64+g] + r*(pn + bn));
        float hnew = n + z*(hbuf0[p][eg] - n);
        st_rlx64(&ring0[(size_t)((t+1) & R0M)*HID + eg],
                 pack_tv((unsigned)(t+1), hnew));
        if (t == T_STEPS-1) d_out[T_STEPS + eg] = hnew;
      }
      // write the prefetched ig slice for step t+1 (ordered by next barrier)
      if (tid < 96) igbuf[p ^ 1][tid] = igpre;
    }
  } else {
    // ================= stage B: layer-1 GRU =================
    const int wg  = (int)blockIdx.x - 16;  // 0..31
    const int g   = tid >> 5;              // 0..15: element group
    const int j32 = tid & 31;
    const int half = j32 >> 4;             // 0 = ih (reads h0), 1 = hh (reads h1)
    const int jj  = j32 & 15;
    const int eg  = wg*16 + g;             // global h1 element
    const bool leader = (j32 == 0);
    const float* Wm = half ? w_hh1 : w_ih1;
    float4 ar[8], az[8], an[8];
    {
      const float4* pr_ = (const float4*)(Wm + (size_t)eg*HID);
      const float4* pz_ = (const float4*)(Wm + (size_t)(512+eg)*HID);
      const float4* pn_ = (const float4*)(Wm + (size_t)(1024+eg)*HID);
#pragma unroll
      for (int i = 0; i < 8; i++) {
        ar[i] = pr_[jj + 16*i]; az[i] = pz_[jj + 16*i]; an[i] = pn_[jj + 16*i];
        pin4(ar[i]); pin4(az[i]); pin4(an[i]);
      }
    }
    const float cr = b_ih1[eg], cz = b_ih1[512+eg], cn = b_ih1[1024+eg];
    const float bnn = b_n1[eg];
    for (int t = 0; t < T_STEPS; t++) {
      const int p = t & 1;
      // stage h0^(t) [tag t+1] and h1^(t-1) [tag t]; issue both probes first
      const unsigned long long* s0 = &ring0[(size_t)((t+1) & R0M)*HID + tid];
      const unsigned long long* s1 = &ring1[(size_t)(t & R1M)*HID + tid];
      const unsigned w0t = (unsigned)(t+1), w1t = (unsigned)t;
      unsigned long long v0 = ld_rlx64(s0);
      unsigned long long v1 = ld_rlx64(s1);
      while ((unsigned)(v0 >> 32) != w0t) { __builtin_amdgcn_s_sleep(1); v0 = ld_rlx64(s0); }
      while ((unsigned)(v1 >> 32) != w1t) { __builtin_amdgcn_s_sleep(1); v1 = ld_rlx64(s1); }
      hbuf0[p][tid] = __uint_as_float((unsigned)v0);
      hbuf1[p][tid] = __uint_as_float((unsigned)v1);
      __syncthreads();   // the ONLY barrier per step
      const float4* hp = (const float4*)(half ? hbuf1[p] : hbuf0[p]);
      float pr=0.f, pz=0.f, pn=0.f;
#pragma unroll
      for (int i = 0; i < 8; i++) {
        float4 hv = hp[jj + 16*i];
        pr += dot4(ar[i],hv); pz += dot4(az[i],hv); pn += dot4(an[i],hv);
      }
#pragma unroll
      for (int s = 1; s < 16; s <<= 1) {   // width 16: halves reduce separately
        pr += __shfl_xor(pr, s, 16);
        pz += __shfl_xor(pz, s, 16);
        pn += __shfl_xor(pn, s, 16);
      }
      // harvest hh-half sums (lane 16 of the 32-lane group)
      float qr = __shfl(pr, 16, 32);
      float qz = __shfl(pz, 16, 32);
      float qn = __shfl(pn, 16, 32);
      if (leader) {
        float r = fast_sigmoid(pr + cr + qr);
        float z = fast_sigmoid(pz + cz + qz);
        float n = fast_tanh(pn + cn + r*(qn + bnn));
        float hnew = n + z*(hbuf1[p][eg] - n);
        st_rlx64(&ring1[(size_t)((t+1) & R1M)*HID + eg],
                 pack_tv((unsigned)(t+1), hnew));
        h1a[(size_t)t*HID + eg] = hnew;   // plain store for the MLP kernel
        if (t == T_STEPS-1) d_out[T_STEPS + HID + eg] = hnew;
      }
      if (tid == 0 && (t & 31) == 31)
        st_rlx32(&cntB[wg], (unsigned)(t+1));   // throttle progress (coarse)
    }
  }
}

// ---- k4: batched MLP head --------------------------------------------------
__global__ __launch_bounds__(64) void mlp_kernel(
    const float* __restrict__ h1_all, const float* __restrict__ mw0,
    const float* __restrict__ mb0, const float* __restrict__ mw1,
    const float* __restrict__ mb1, const float* __restrict__ mw2,
    const float* __restrict__ mb2, float* __restrict__ out) {
  const int l = threadIdx.x;
  const int t0 = blockIdx.x * 8;
  __shared__ float v0s[8][64];
  float acc[8];
#pragma unroll
  for (int tt = 0; tt < 8; tt++) acc[tt] = mb0[l];
  const float4* w = (const float4*)(mw0 + (size_t)l*512);
#pragma unroll 4
  for (int i = 0; i < 128; i++) {
    float4 a = w[i];
#pragma unroll
    for (int tt = 0; tt < 8; tt++) {
      float4 b = ((const float4*)(h1_all + (size_t)(t0+tt)*512))[i];
      acc[tt] = fmaf(a.x,b.x, fmaf(a.y,b.y, fmaf(a.z,b.z, fmaf(a.w,b.w, acc[tt]))));
    }
  }
#pragma unroll
  for (int tt = 0; tt < 8; tt++) v0s[tt][l] = fmaxf(acc[tt], 0.f);
  __syncthreads();
  float acc1[8];
#pragma unroll
  for (int tt = 0; tt < 8; tt++) acc1[tt] = mb1[l];
  const float* w1 = mw1 + (size_t)l*64;
  for (int jj = 0; jj < 64; jj++) {
    float wv = w1[jj];
#pragma unroll
    for (int tt = 0; tt < 8; tt++) acc1[tt] = fmaf(wv, v0s[tt][jj], acc1[tt]);
  }
  float w2 = mw2[l];
  float bb = mb2[0];
#pragma unroll
  for (int tt = 0; tt < 8; tt++) {
    float y = w2 * fmaxf(acc1[tt], 0.f);
#pragma unroll
    for (int s = 32; s > 0; s >>= 1) y += __shfl_down(y, s, 64);
    if (l == 0) out[t0+tt] = y + bb;
  }
}

// ---------------------------------------------------------------------------
extern "C" void kernel_launch(void* const* d_in, const int* in_sizes, int n_in,
                              void* d_out, int out_size, void* d_ws, size_t ws_size,
                              hipStream_t stream) {
  const float* p0  = (const float*)d_in[0];
  const float* p1  = (const float*)d_in[1];
  const float* p2  = (const float*)d_in[2];
  const float* p3  = (const float*)d_in[3];
  const float* p4  = (const float*)d_in[4];
  const float* p5  = (const float*)d_in[5];
  const float* p6  = (const float*)d_in[6];
  const float* p7  = (const float*)d_in[7];
  const float* p8  = (const float*)d_in[8];
  const float* p9  = (const float*)d_in[9];
  const float* p10 = (const float*)d_in[10];
  const float* p11 = (const float*)d_in[11];
  const float* p12 = (const float*)d_in[12];
  const float* hid   = (const float*)d_in[13];
  const float* w_ih0 = (const float*)d_in[14];
  const float* w_hh0 = (const float*)d_in[15];
  const float* b_ih0 = (const float*)d_in[16];
  const float* b_n0  = (const float*)d_in[17];
  const float* w_ih1 = (const float*)d_in[18];
  const float* w_hh1 = (const float*)d_in[19];
  const float* b_ih1 = (const float*)d_in[20];
  const float* b_n1  = (const float*)d_in[21];
  const float* mw0 = (const float*)d_in[22];
  const float* mb0 = (const float*)d_in[23];
  const float* mw1 = (const float*)d_in[24];
  const float* mb1 = (const float*)d_in[25];
  const float* mw2 = (const float*)d_in[26];
  const float* mb2 = (const float*)d_in[27];
  float* out = (float*)d_out;

  // workspace: ig0 | ring0 | ring1 | cntB | h1a  (obs/wT alias h1a region)
  char* base = (char*)d_ws;
  const size_t IG0_B = (size_t)T_STEPS*G3*4;     // 100,663,296
  const size_t R0_B  = (size_t)R0*HID*8;         //   8,388,608
  const size_t R1_B  = (size_t)R1*HID*8;         //      32,768
  const size_t CNT_B = 1024;
  const size_t H1A_B = (size_t)T_STEPS*HID*4;    //  33,554,432
  float* ig0 = (float*)base;
  unsigned long long* ring0 = (unsigned long long*)(base + IG0_B);
  unsigned long long* ring1 = (unsigned long long*)(base + IG0_B + R0_B);
  unsigned* cntB = (unsigned*)(base + IG0_B + R0_B + R1_B);
  float* h1a = (float*)(base + IG0_B + R0_B + R1_B + CNT_B);
  float* obs = h1a;                                              // alias
  float* wT  = (float*)((char*)h1a + (size_t)T_STEPS*IN_DIM*4);  // alias
  if (ws_size < IG0_B + R0_B + R1_B + CNT_B + H1A_B) return;

  hipMemsetAsync(cntB, 0, CNT_B, stream);
  concat_kernel<<<T_STEPS, 384, 0, stream>>>(p0,p1,p2,p3,p4,p5,p6,p7,p8,p9,p10,p11,p12, obs);
  transpose_kernel<<<dim3(11,48), dim3(32,8), 0, stream>>>(w_ih0, wT);
  ig0_kernel<<<dim3(6, T_STEPS/TTILE), 256, 0, stream>>>(wT, obs, b_ih0, ig0);
  init_kernel<<<1, 512, 0, stream>>>(hid, ring0, ring1);
  seq_kernel<<<48, 512, 0, stream>>>(ig0, w_hh0, b_n0, w_ih1, w_hh1, b_ih1, b_n1,
                                     ring0, ring1, cntB, h1a, out);
  mlp_kernel<<<T_STEPS/8, 64, 0, stream>>>(h1a, mw0, mb0, mw1, mb1, mw2, mb2, out);
}